// Round 1
// baseline (5402.560 us; speedup 1.0000x reference)
//
#include <hip/hip_runtime.h>
#include <math.h>

#define NP   10
#define C_   64
#define H_   128
#define W_   128
#define HW   (H_*W_)
#define DG_  16
#define CG_  4
#define K_   9
#define MRM_ 10.0f
#define CIN1 130
#define CO4  432

#define S1 (130*9*64)
#define S2 (64*9*64)
#define S4 (64*9*432)

// ---------- frame-mapping helpers ----------
__device__ __forceinline__ const float* xi_base(const float* x, int n) {
    int f = (n < 5) ? (n + 1) : (n - 5);
    return x + (size_t)f * C_ * HW;
}
__device__ __forceinline__ const float* cur_base(const float* x, int n) {
    int f = (n < 5) ? n : (n - 4);
    return x + (size_t)f * C_ * HW;
}
__device__ __forceinline__ const float* fl_base(const float* fb, const float* ff, int n) {
    return (n < 5) ? (fb + (size_t)n * 2 * HW) : (ff + (size_t)(n - 5) * 2 * HW);
}

// ---------- bilinear corner helper (zero padding outside) ----------
struct Bil { int i00, i01, i10, i11; float m00, m01, m10, m11; };
__device__ __forceinline__ Bil bil(float py, float px) {
    float y0f = floorf(py), x0f = floorf(px);
    int iy0 = (int)y0f, ix0 = (int)x0f;
    float ay = py - y0f, ax = px - x0f;
    bool v0y = (unsigned)iy0 < (unsigned)H_;
    bool v1y = (unsigned)(iy0 + 1) < (unsigned)H_;
    bool v0x = (unsigned)ix0 < (unsigned)W_;
    bool v1x = (unsigned)(ix0 + 1) < (unsigned)W_;
    int cy0 = min(max(iy0, 0), H_ - 1), cy1 = min(max(iy0 + 1, 0), H_ - 1);
    int cx0 = min(max(ix0, 0), W_ - 1), cx1 = min(max(ix0 + 1, 0), W_ - 1);
    Bil r;
    r.m00 = (1.f - ay) * (1.f - ax) * (float)(v0y && v0x);
    r.m01 = (1.f - ay) * ax         * (float)(v0y && v1x);
    r.m10 = ay * (1.f - ax)         * (float)(v1y && v0x);
    r.m11 = ay * ax                 * (float)(v1y && v1x);
    r.i00 = cy0 * W_ + cx0; r.i01 = cy0 * W_ + cx1;
    r.i10 = cy1 * W_ + cx0; r.i11 = cy1 * W_ + cx1;
    return r;
}

// ---------- weight transpose prep ----------
// cw1t/cw2t/cw3t: [ci][k][co64]; cw4t: [ci][k][ch432]; dwt: [(g*4+c)][k][o64]
__global__ __launch_bounds__(256) void k_prep(
        const float* __restrict__ cw1, const float* __restrict__ cw2,
        const float* __restrict__ cw3, const float* __restrict__ cw4,
        const float* __restrict__ dw,
        float* __restrict__ cw1t, float* __restrict__ cw2t,
        float* __restrict__ cw3t, float* __restrict__ cw4t,
        float* __restrict__ dwt) {
    int id = blockIdx.x * 256 + threadIdx.x;
    if (id < S1) {
        int co = id & 63, r = id >> 6; int k = r % 9, ci = r / 9;
        cw1t[id] = cw1[(co * 130 + ci) * 9 + k]; return;
    }
    id -= S1;
    if (id < S2) {
        int co = id & 63, r = id >> 6; int k = r % 9, ci = r / 9;
        cw2t[id] = cw2[(co * 64 + ci) * 9 + k]; return;
    }
    id -= S2;
    if (id < S2) {
        int co = id & 63, r = id >> 6; int k = r % 9, ci = r / 9;
        cw3t[id] = cw3[(co * 64 + ci) * 9 + k]; return;
    }
    id -= S2;
    if (id < S4) {
        int ch = id % 432, r = id / 432; int k = r % 9, ci = r / 9;
        cw4t[id] = cw4[(ch * 64 + ci) * 9 + k]; return;
    }
    id -= S4;
    if (id < S2) {
        int o = id & 63, r = id >> 6; int k = r % 9, ci = r / 9;
        dwt[id] = dw[(o * 64 + ci) * 9 + k]; return;
    }
}

// ---------- flow warp: warped[n][c][y][x] ----------
__global__ __launch_bounds__(256) void k_warp(
        const float* __restrict__ x, const float* __restrict__ fb,
        const float* __restrict__ ff, float* __restrict__ warped) {
    int gid = blockIdx.x * 256 + threadIdx.x;
    int n = gid / HW, pos = gid % HW;
    int y = pos / W_, xx = pos % W_;
    const float* fl = fl_base(fb, ff, n);
    float fx = fl[pos], fy = fl[HW + pos];
    Bil b = bil((float)y + fy, (float)xx + fx);
    const float* xb = xi_base(x, n);
    float* wout = warped + (size_t)n * C_ * HW + pos;
    for (int c = 0; c < C_; ++c) {
        const float* p = xb + c * HW;
        wout[c * HW] = b.m00 * p[b.i00] + b.m01 * p[b.i01]
                     + b.m10 * p[b.i10] + b.m11 * p[b.i11];
    }
}

// ---------- generic 3x3 conv, 64 out channels, LeakyReLU(0.1) ----------
// SRC==0: conv1 (ci<64: warped buf; 64..127: cur frame of x; 128..129: flow)
// SRC==1: single input buffer [n][64][H][W]
template<int CIN, int SRC>
__global__ __launch_bounds__(256) void k_conv(
        const float* __restrict__ in, const float* __restrict__ x,
        const float* __restrict__ fb, const float* __restrict__ ff,
        const float* __restrict__ wt, const float* __restrict__ bias,
        float* __restrict__ outp) {
    __shared__ __align__(16) float tile[18 * 18];
    __shared__ __align__(16) float wl[9 * 64];
    int tid = threadIdx.x;
    int bx = blockIdx.x & 7, by = (blockIdx.x >> 3) & 7, n = blockIdx.x >> 6;
    int tx = tid & 15, ty = tid >> 4;
    int X = bx * 16 + tx, Y = by * 16 + ty;
    float acc[64];
    #pragma unroll
    for (int i = 0; i < 64; ++i) acc[i] = 0.f;

    for (int ci = 0; ci < CIN; ++ci) {
        const float* src;
        if (SRC == 0) {
            if (ci < 64)       src = in + ((size_t)n * 64 + ci) * HW;
            else if (ci < 128) src = cur_base(x, n) + (size_t)(ci - 64) * HW;
            else               src = fl_base(fb, ff, n) + (size_t)(ci - 128) * HW;
        } else {
            src = in + ((size_t)n * 64 + ci) * HW;
        }
        for (int i = tid; i < 18 * 18; i += 256) {
            int yy = i / 18, xx = i % 18;
            int gy = by * 16 + yy - 1, gx = bx * 16 + xx - 1;
            tile[i] = (gy >= 0 && gy < H_ && gx >= 0 && gx < W_) ? src[gy * W_ + gx] : 0.f;
        }
        for (int i = tid; i < 576; i += 256) wl[i] = wt[(size_t)ci * 576 + i];
        __syncthreads();

        float win[9];
        #pragma unroll
        for (int ky = 0; ky < 3; ++ky)
            #pragma unroll
            for (int kx = 0; kx < 3; ++kx)
                win[ky * 3 + kx] = tile[(ty + ky) * 18 + tx + kx];

        #pragma unroll
        for (int k = 0; k < 9; ++k) {
            float wv = win[k];
            #pragma unroll
            for (int c4 = 0; c4 < 16; ++c4) {
                float4 wq = *(const float4*)&wl[k * 64 + c4 * 4];
                acc[c4 * 4 + 0] += wq.x * wv;
                acc[c4 * 4 + 1] += wq.y * wv;
                acc[c4 * 4 + 2] += wq.z * wv;
                acc[c4 * 4 + 3] += wq.w * wv;
            }
        }
        __syncthreads();
    }
    float* op = outp + (size_t)n * 64 * HW + Y * W_ + X;
    #pragma unroll
    for (int co = 0; co < 64; ++co) {
        float v = acc[co] + bias[co];
        v = (v >= 0.f) ? v : 0.1f * v;
        op[co * HW] = v;
    }
}

// ---------- fused conv4 + tanh/sigmoid + flow-add + modulated deformable conv ----------
// block = 8x8 pixel tile, 256 threads = 64 px * 4 subs (sub == wave id)
__global__ __launch_bounds__(256) void k_dcn(
        const float* __restrict__ h3, const float* __restrict__ x,
        const float* __restrict__ fb, const float* __restrict__ ff,
        const float* __restrict__ cw4t, const float* __restrict__ cb4,
        const float* __restrict__ dwt, const float* __restrict__ db,
        float* __restrict__ outb) {
    __shared__ float hl[64 * 100];   // h3 halo tile [ci][10][10]
    __shared__ float om[27 * 64];    // per-group offsets/mask [jc][px]
    __shared__ float sv[36 * 64];    // samples*mask [(k*4+c)][px]

    int tid = threadIdx.x;
    int px = tid & 63;
    int sub = __builtin_amdgcn_readfirstlane(tid >> 6);  // wave-uniform
    int bx = blockIdx.x & 15, by = (blockIdx.x >> 4) & 15, n = blockIdx.x >> 8;
    int tx = px & 7, ty = px >> 3;
    int X = bx * 8 + tx, Y = by * 8 + ty;

    const float* h3n = h3 + (size_t)n * 64 * HW;
    for (int i = tid; i < 6400; i += 256) {
        int ci = i / 100, pos = i % 100;
        int yy = pos / 10, xx = pos % 10;
        int gy = by * 8 + yy - 1, gx = bx * 8 + xx - 1;
        hl[i] = (gy >= 0 && gy < H_ && gx >= 0 && gx < W_) ? h3n[(size_t)ci * HW + gy * W_ + gx] : 0.f;
    }
    const float* fl = fl_base(fb, ff, n);
    float fx = fl[Y * W_ + X], fy = fl[HW + Y * W_ + X];
    const float* xg0 = xi_base(x, n);

    float acc[16];
    #pragma unroll
    for (int i = 0; i < 16; ++i) acc[i] = 0.f;
    int rowbase = ty * 10 + tx;
    __syncthreads();

    for (int g = 0; g < 16; ++g) {
        // ---- phase A: conv4 for this group's 27 channels -> om[27][64]
        float a7[7];
        #pragma unroll
        for (int i = 0; i < 7; ++i) a7[i] = 0.f;
        for (int cc = 0; cc < 16; ++cc) {
            float win[36];
            #pragma unroll
            for (int i4 = 0; i4 < 4; ++i4) {
                int ci = cc * 4 + i4;
                #pragma unroll
                for (int ky = 0; ky < 3; ++ky)
                    #pragma unroll
                    for (int kx = 0; kx < 3; ++kx)
                        win[i4 * 9 + ky * 3 + kx] = hl[ci * 100 + ky * 10 + kx + rowbase];
            }
            #pragma unroll
            for (int i = 0; i < 7; ++i) {
                int jc = sub + 4 * i;
                if (jc < 27) {
                    int ch = (jc < 18) ? (g * 18 + jc) : (288 + g * 9 + (jc - 18));
                    const float* wp = cw4t + (size_t)(cc * 4) * 9 * 432 + ch;
                    #pragma unroll
                    for (int i4 = 0; i4 < 4; ++i4)
                        #pragma unroll
                        for (int k = 0; k < 9; ++k)
                            a7[i] += wp[(i4 * 9 + k) * 432] * win[i4 * 9 + k];
                }
            }
        }
        #pragma unroll
        for (int i = 0; i < 7; ++i) {
            int jc = sub + 4 * i;
            if (jc < 27) {
                int ch = (jc < 18) ? (g * 18 + jc) : (288 + g * 9 + (jc - 18));
                float v = a7[i] + cb4[ch];
                if (jc < 18) v = MRM_ * tanhf(v) + ((jc & 1) ? fx : fy);
                else         v = 1.f / (1.f + expf(-v));
                om[jc * 64 + px] = v;
            }
        }
        __syncthreads();

        // ---- phase B0: bilinear sampling * mask -> sv[36][64] (waves 0..2, 3 taps each)
        if (sub < 3) {
            #pragma unroll
            for (int kk = 0; kk < 3; ++kk) {
                int k = sub * 3 + kk;
                float oy = om[(2 * k) * 64 + px];
                float ox = om[(2 * k + 1) * 64 + px];
                float mk = om[(18 + k) * 64 + px];
                float py = (float)Y - 1.f + (float)(k / 3) + oy;
                float pxx = (float)X - 1.f + (float)(k % 3) + ox;
                Bil b = bil(py, pxx);
                const float* gb = xg0 + (size_t)(g * 4) * HW;
                #pragma unroll
                for (int c = 0; c < 4; ++c) {
                    const float* p = gb + (size_t)c * HW;
                    float s = b.m00 * p[b.i00] + b.m01 * p[b.i01]
                            + b.m10 * p[b.i10] + b.m11 * p[b.i11];
                    sv[(k * 4 + c) * 64 + px] = s * mk;
                }
            }
        }
        __syncthreads();

        // ---- phase B1: acc[o] += sum_{c,k} sv * dwt[g][c][k][o]
        #pragma unroll
        for (int c = 0; c < 4; ++c) {
            #pragma unroll
            for (int k = 0; k < 9; ++k) {
                float v = sv[(k * 4 + c) * 64 + px];
                const float* wp = dwt + (size_t)((g * 4 + c) * 9 + k) * 64 + sub * 16;
                #pragma unroll
                for (int o = 0; o < 16; ++o) acc[o] += v * wp[o];
            }
        }
        __syncthreads();
    }

    // ---- epilogue: bias + scatter to output frames
    float* base;
    if (n < 5) base = outb + (size_t)n * 64 * HW;                       // x_backward frame n
    else       base = outb + (size_t)6 * 64 * HW + (size_t)(n - 4) * 64 * HW; // x_forward frame n-4
    #pragma unroll
    for (int o16 = 0; o16 < 16; ++o16) {
        int o = sub * 16 + o16;
        base[(size_t)o * HW + Y * W_ + X] = acc[o16] + db[o];
    }
}

extern "C" void kernel_launch(void* const* d_in, const int* in_sizes, int n_in,
                              void* d_out, int out_size, void* d_ws, size_t ws_size,
                              hipStream_t stream) {
    (void)in_sizes; (void)n_in; (void)out_size; (void)ws_size;
    const float* x   = (const float*)d_in[0];
    const float* fb  = (const float*)d_in[1];
    const float* ff  = (const float*)d_in[2];
    const float* cw1 = (const float*)d_in[3];
    const float* cb1 = (const float*)d_in[4];
    const float* cw2 = (const float*)d_in[5];
    const float* cb2 = (const float*)d_in[6];
    const float* cw3 = (const float*)d_in[7];
    const float* cb3 = (const float*)d_in[8];
    const float* cw4 = (const float*)d_in[9];
    const float* cb4 = (const float*)d_in[10];
    const float* dw  = (const float*)d_in[11];
    const float* db  = (const float*)d_in[12];
    float* out = (float*)d_out;
    float* ws  = (float*)d_ws;

    // Ping buffer A lives in d_out (dead before final writes); B + weights in ws.
    float* bufA = out;                       // 10,485,760 floats
    float* bufB = ws;                        // 10,485,760 floats
    float* cw1t = ws + 10485760;
    float* cw2t = cw1t + S1;
    float* cw3t = cw2t + S2;
    float* cw4t = cw3t + S2;
    float* dwt  = cw4t + S4;

    k_prep<<<(S1 + 3 * S2 + S4 + 255) / 256, 256, 0, stream>>>(
        cw1, cw2, cw3, cw4, dw, cw1t, cw2t, cw3t, cw4t, dwt);
    k_warp<<<(NP * HW) / 256, 256, 0, stream>>>(x, fb, ff, bufA);
    k_conv<130, 0><<<640, 256, 0, stream>>>(bufA, x, fb, ff, cw1t, cb1, bufB);
    k_conv<64, 1><<<640, 256, 0, stream>>>(bufB, x, fb, ff, cw2t, cb2, bufA);
    k_conv<64, 1><<<640, 256, 0, stream>>>(bufA, x, fb, ff, cw3t, cb3, bufB);

    // zero frames (inside former bufA region -> must come after conv3 consumed bufA)
    hipMemsetAsync((char*)d_out + (size_t)5 * C_ * HW * sizeof(float), 0, (size_t)C_ * HW * sizeof(float), stream);
    hipMemsetAsync((char*)d_out + (size_t)6 * C_ * HW * sizeof(float), 0, (size_t)C_ * HW * sizeof(float), stream);

    k_dcn<<<2560, 256, 0, stream>>>(bufB, x, fb, ff, cw4t, cb4, dwt, db, out);
}

// Round 2
// 1991.484 us; speedup vs baseline: 2.7128x; 2.7128x over previous
//
#include <hip/hip_runtime.h>
#include <math.h>

#define NP   10
#define C_   64
#define H_   128
#define W_   128
#define HW   (H_*W_)
#define DG_  16
#define CG_  4
#define K_   9
#define MRM_ 10.0f

#define S1 (130*9*64)
#define S2 (64*9*64)

typedef __bf16 bf16x8 __attribute__((ext_vector_type(8)));
typedef float  f32x16 __attribute__((ext_vector_type(16)));

__device__ __forceinline__ f32x16 mfma32(bf16x8 a, bf16x8 b, f32x16 c) {
    return __builtin_amdgcn_mfma_f32_32x32x16_bf16(a, b, c, 0, 0, 0);
}

__device__ __forceinline__ ushort bfrn(float f) {
    uint u = __builtin_bit_cast(uint, f);
    u += 0x7FFFu + ((u >> 16) & 1u);
    return (ushort)(u >> 16);
}
__device__ __forceinline__ float bf2f(ushort h) {
    uint u = (uint)h << 16; return __builtin_bit_cast(float, u);
}
__device__ __forceinline__ float fast_tanh(float x) {
    float e = __expf(2.f * x);
    return 1.f - 2.f / (e + 1.f);
}

// ---------- frame-mapping helpers ----------
__device__ __forceinline__ const float* xi_base(const float* x, int n) {
    int f = (n < 5) ? (n + 1) : (n - 5);
    return x + (size_t)f * C_ * HW;
}
__device__ __forceinline__ const float* cur_base(const float* x, int n) {
    int f = (n < 5) ? n : (n - 4);
    return x + (size_t)f * C_ * HW;
}
__device__ __forceinline__ const float* fl_base(const float* fb, const float* ff, int n) {
    return (n < 5) ? (fb + (size_t)n * 2 * HW) : (ff + (size_t)(n - 5) * 2 * HW);
}

// ---------- bilinear corner helper (zero padding outside) ----------
struct Bil { int i00, i01, i10, i11; float m00, m01, m10, m11; };
__device__ __forceinline__ Bil bil(float py, float px) {
    float y0f = floorf(py), x0f = floorf(px);
    int iy0 = (int)y0f, ix0 = (int)x0f;
    float ay = py - y0f, ax = px - x0f;
    bool v0y = (unsigned)iy0 < (unsigned)H_;
    bool v1y = (unsigned)(iy0 + 1) < (unsigned)H_;
    bool v0x = (unsigned)ix0 < (unsigned)W_;
    bool v1x = (unsigned)(ix0 + 1) < (unsigned)W_;
    int cy0 = min(max(iy0, 0), H_ - 1), cy1 = min(max(iy0 + 1, 0), H_ - 1);
    int cx0 = min(max(ix0, 0), W_ - 1), cx1 = min(max(ix0 + 1, 0), W_ - 1);
    Bil r;
    r.m00 = (1.f - ay) * (1.f - ax) * (float)(v0y && v0x);
    r.m01 = (1.f - ay) * ax         * (float)(v0y && v1x);
    r.m10 = ay * (1.f - ax)         * (float)(v1y && v0x);
    r.m11 = ay * ax                 * (float)(v1y && v1x);
    r.i00 = cy0 * W_ + cx0; r.i01 = cy0 * W_ + cx1;
    r.i10 = cy1 * W_ + cx0; r.i11 = cy1 * W_ + cx1;
    return r;
}

// ---------- weight transpose prep (f32, conv1-3) ----------
__global__ __launch_bounds__(256) void k_prep1(
        const float* __restrict__ cw1, const float* __restrict__ cw2,
        const float* __restrict__ cw3,
        float* __restrict__ cw1t, float* __restrict__ cw2t,
        float* __restrict__ cw3t) {
    int id = blockIdx.x * 256 + threadIdx.x;
    if (id < S1) {
        int co = id & 63, r = id >> 6; int k = r % 9, ci = r / 9;
        cw1t[id] = cw1[(co * 130 + ci) * 9 + k]; return;
    }
    id -= S1;
    if (id < S2) {
        int co = id & 63, r = id >> 6; int k = r % 9, ci = r / 9;
        cw2t[id] = cw2[(co * 64 + ci) * 9 + k]; return;
    }
    id -= S2;
    if (id < S2) {
        int co = id & 63, r = id >> 6; int k = r % 9, ci = r / 9;
        cw3t[id] = cw3[(co * 64 + ci) * 9 + k]; return;
    }
}

// ---------- MFMA fragment-order weight prep (conv4 hi/lo + dcn + bias) ----------
// w4hi/w4lo: blocks ((c*9+t)*16+g) of 512 elems; elem (l,j): k=(l>>5)*8+j -> ci=c*16+k; n=l&31 -> channel map
// dwtb: blocks ((g*3+kst)*2+nf) of 512; k-index kk=kst*16+(l>>5)*8+j = t*4+cc (pad>=36 zero); oc=nf*32+(l&31)
__global__ __launch_bounds__(256) void k_prep4(
        const float* __restrict__ cw4, const float* __restrict__ cb4,
        const float* __restrict__ dw,
        ushort* __restrict__ w4hi, ushort* __restrict__ w4lo,
        ushort* __restrict__ dwtb, float* __restrict__ pb4) {
    int id = blockIdx.x * 256 + threadIdx.x;
    if (id < 294912) {
        int blk = id >> 9, e = id & 511;
        int c = blk / 144, r = blk - c * 144;
        int t = r >> 4, g = r & 15;
        int l = e >> 3, j = e & 7;
        int n = l & 31, kh = l >> 5;
        int ci = c * 16 + kh * 8 + j;
        int ch = (n < 18) ? g * 18 + n : (n < 27 ? 288 + g * 9 + (n - 18) : -1);
        float v = (ch >= 0) ? cw4[((size_t)ch * 64 + ci) * 9 + t] : 0.f;
        ushort h = bfrn(v);
        w4hi[id] = h;
        w4lo[id] = bfrn(v - bf2f(h));
        return;
    }
    id -= 294912;
    if (id < 49152) {
        int blk = id >> 9, e = id & 511;
        int g = blk / 6, r = blk - g * 6;
        int kst = r >> 1, nf = r & 1;
        int l = e >> 3, j = e & 7;
        int kk = kst * 16 + (l >> 5) * 8 + j;
        int oc = nf * 32 + (l & 31);
        float v = (kk < 36) ? dw[((size_t)oc * 64 + g * 4 + (kk & 3)) * 9 + (kk >> 2)] : 0.f;
        dwtb[id] = bfrn(v);
        return;
    }
    id -= 49152;
    if (id < 512) {
        int g = id >> 5, n = id & 31;
        int ch = (n < 18) ? g * 18 + n : (n < 27 ? 288 + g * 9 + (n - 18) : -1);
        pb4[id] = (ch >= 0) ? cb4[ch] : 0.f;
    }
}

// ---------- flow warp ----------
__global__ __launch_bounds__(256) void k_warp(
        const float* __restrict__ x, const float* __restrict__ fb,
        const float* __restrict__ ff, float* __restrict__ warped) {
    int gid = blockIdx.x * 256 + threadIdx.x;
    int n = gid / HW, pos = gid % HW;
    int y = pos / W_, xx = pos % W_;
    const float* fl = fl_base(fb, ff, n);
    float fx = fl[pos], fy = fl[HW + pos];
    Bil b = bil((float)y + fy, (float)xx + fx);
    const float* xb = xi_base(x, n);
    float* wout = warped + (size_t)n * C_ * HW + pos;
    for (int c = 0; c < C_; ++c) {
        const float* p = xb + c * HW;
        wout[c * HW] = b.m00 * p[b.i00] + b.m01 * p[b.i01]
                     + b.m10 * p[b.i10] + b.m11 * p[b.i11];
    }
}

// ---------- generic 3x3 conv (f32 VALU), 64 out channels, LeakyReLU(0.1) ----------
template<int CIN, int SRC>
__global__ __launch_bounds__(256) void k_conv(
        const float* __restrict__ in, const float* __restrict__ x,
        const float* __restrict__ fb, const float* __restrict__ ff,
        const float* __restrict__ wt, const float* __restrict__ bias,
        float* __restrict__ outp) {
    __shared__ __align__(16) float tile[18 * 18];
    __shared__ __align__(16) float wl[9 * 64];
    int tid = threadIdx.x;
    int bx = blockIdx.x & 7, by = (blockIdx.x >> 3) & 7, n = blockIdx.x >> 6;
    int tx = tid & 15, ty = tid >> 4;
    int X = bx * 16 + tx, Y = by * 16 + ty;
    float acc[64];
    #pragma unroll
    for (int i = 0; i < 64; ++i) acc[i] = 0.f;

    for (int ci = 0; ci < CIN; ++ci) {
        const float* src;
        if (SRC == 0) {
            if (ci < 64)       src = in + ((size_t)n * 64 + ci) * HW;
            else if (ci < 128) src = cur_base(x, n) + (size_t)(ci - 64) * HW;
            else               src = fl_base(fb, ff, n) + (size_t)(ci - 128) * HW;
        } else {
            src = in + ((size_t)n * 64 + ci) * HW;
        }
        for (int i = tid; i < 18 * 18; i += 256) {
            int yy = i / 18, xx = i % 18;
            int gy = by * 16 + yy - 1, gx = bx * 16 + xx - 1;
            tile[i] = (gy >= 0 && gy < H_ && gx >= 0 && gx < W_) ? src[gy * W_ + gx] : 0.f;
        }
        for (int i = tid; i < 576; i += 256) wl[i] = wt[(size_t)ci * 576 + i];
        __syncthreads();

        float win[9];
        #pragma unroll
        for (int ky = 0; ky < 3; ++ky)
            #pragma unroll
            for (int kx = 0; kx < 3; ++kx)
                win[ky * 3 + kx] = tile[(ty + ky) * 18 + tx + kx];

        #pragma unroll
        for (int k = 0; k < 9; ++k) {
            float wv = win[k];
            #pragma unroll
            for (int c4 = 0; c4 < 16; ++c4) {
                float4 wq = *(const float4*)&wl[k * 64 + c4 * 4];
                acc[c4 * 4 + 0] += wq.x * wv;
                acc[c4 * 4 + 1] += wq.y * wv;
                acc[c4 * 4 + 2] += wq.z * wv;
                acc[c4 * 4 + 3] += wq.w * wv;
            }
        }
        __syncthreads();
    }
    float* op = outp + (size_t)n * 64 * HW + Y * W_ + X;
    #pragma unroll
    for (int co = 0; co < 64; ++co) {
        float v = acc[co] + bias[co];
        v = (v >= 0.f) ? v : 0.1f * v;
        op[co * HW] = v;
    }
}

// ================== fused conv4(bf16x2 MFMA) + sampler(f32) + DCN GEMM(bf16 MFMA) ==================
// block = 16x16 px tile, 256 threads = 4 waves; wave w owns px rows 4w..4w+3 (Mfrags 2w,2w+1)
__global__ __launch_bounds__(256, 2) void k_dcn2(
        const float* __restrict__ h3, const float* __restrict__ x,
        const float* __restrict__ fb, const float* __restrict__ ff,
        const ushort* __restrict__ w4hi, const ushort* __restrict__ w4lo,
        const ushort* __restrict__ dwtb, const float* __restrict__ pb4,
        const float* __restrict__ db, float* __restrict__ outb) {
    // LDS plan (61 KiB):
    //  [0,10368)      Ahi  : h3 halo tile hi, [cell 324][ci 16] bf16, XOR-swizzled
    //  [10368,20736)  Alo  : same, lo plane
    //  [0,32768)      SVB  : sv [px 256][64] bf16 swizzled (overlays A during sample/gemm phases)
    //  [32768,60416)  OMB  : om [px 256][27] f32 (stride 27 -> conflict-free)
    //  [60416,62464)  FLT  : fx[256], fy[256]
    __shared__ __align__(16) char lds[62464];
    float* OMB = (float*)(lds + 32768);
    float* FLT = (float*)(lds + 60416);

    int tid = threadIdx.x;
    int lane = tid & 63, w = tid >> 6;
    int bx = blockIdx.x & 7, by = (blockIdx.x >> 3) & 7, n = blockIdx.x >> 6;
    int col = lane & 31, khalf = lane >> 5;

    const float* h3n = h3 + (size_t)n * 64 * HW;
    const float* fl = fl_base(fb, ff, n);
    const float* xg0 = xi_base(x, n);

    // ---- stage flow tile + zero sv K-pad slots (kk 36..47 -> units (4,h1),(5,h0),(5,h1))
    {
        int Y = by * 16 + (tid >> 4), X = bx * 16 + (tid & 15);
        FLT[tid] = fl[Y * W_ + X];
        FLT[256 + tid] = fl[HW + Y * W_ + X];
        uint base = (uint)tid * 128, x7 = (uint)(tid & 7);
        *(unsigned long long*)(lds + (base + ((4u ^ x7) << 4) + 8)) = 0ull;
        *(unsigned long long*)(lds + (base + ((5u ^ x7) << 4)))     = 0ull;
        *(unsigned long long*)(lds + (base + ((5u ^ x7) << 4) + 8)) = 0ull;
    }
    __syncthreads();

    f32x16 zero16;
    #pragma unroll
    for (int r = 0; r < 16; ++r) zero16[r] = 0.f;

    f32x16 cd[2][2];   // persistent DCN acc [Mf f][Nf]
    #pragma unroll
    for (int a = 0; a < 2; ++a)
        #pragma unroll
        for (int b = 0; b < 2; ++b) cd[a][b] = zero16;

    int xb2 = col & 15;
    int rb0 = 4 * w + ((col >> 4) & 1);   // + 2*f + ky -> cell row

    for (int sp = 0; sp < 8; ++sp) {
        int g0 = sp * 2;
        f32x16 c4[2][2];   // [gg][f]
        #pragma unroll
        for (int a = 0; a < 2; ++a)
            #pragma unroll
            for (int b = 0; b < 2; ++b) c4[a][b] = zero16;

        for (int c = 0; c < 4; ++c) {
            __syncthreads();   // prev chunk reads / prev gemm sv reads done
            // ---- stage A chunk (ci c*16 .. c*16+15); wave w handles ci' w*4..w*4+3
            for (int v = 0; v < 6; ++v) {
                int cell = v * 64 + lane;
                if (cell < 324) {
                    int cy = cell / 18, cx = cell - cy * 18;
                    int gy = by * 16 + cy - 1, gx = bx * 16 + cx - 1;
                    bool ok = ((unsigned)gy < 128u) && ((unsigned)gx < 128u);
                    const float* srcp = h3n + (size_t)(c * 16 + w * 4) * HW + gy * W_ + gx;
                    uint2 hv, lv;
                    hv.x = hv.y = lv.x = lv.y = 0;
                    #pragma unroll
                    for (int q = 0; q < 4; ++q) {
                        float f = ok ? srcp[q * HW] : 0.f;
                        ushort h = bfrn(f);
                        ushort lo = bfrn(f - bf2f(h));
                        if (q == 0) { hv.x |= h; lv.x |= lo; }
                        else if (q == 1) { hv.x |= (uint)h << 16; lv.x |= (uint)lo << 16; }
                        else if (q == 2) { hv.y |= h; lv.y |= lo; }
                        else { hv.y |= (uint)h << 16; lv.y |= (uint)lo << 16; }
                    }
                    uint byte = (uint)cell * 32 + (uint)w * 8;
                    byte ^= ((byte >> 5) & 7u) << 4;
                    *(uint2*)(lds + byte) = hv;
                    *(uint2*)(lds + 10368 + byte) = lv;
                }
            }
            __syncthreads();
            // ---- 9 taps: B frags direct from global (frag-order packed), A frags from LDS
            #pragma unroll
            for (int t = 0; t < 9; ++t) {
                const int ky = t / 3, kx = t % 3;
                size_t bb = (size_t)((c * 9 + t) * 16) * 512 + (size_t)lane * 8;
                bf16x8 bh0 = *(const bf16x8*)(w4hi + bb + (size_t)g0 * 512);
                bf16x8 bl0 = *(const bf16x8*)(w4lo + bb + (size_t)g0 * 512);
                bf16x8 bh1 = *(const bf16x8*)(w4hi + bb + (size_t)(g0 + 1) * 512);
                bf16x8 bl1 = *(const bf16x8*)(w4lo + bb + (size_t)(g0 + 1) * 512);
                #pragma unroll
                for (int f = 0; f < 2; ++f) {
                    int cell = (rb0 + 2 * f + ky) * 18 + xb2 + kx;
                    uint byte = (uint)cell * 32 + (uint)khalf * 16;
                    byte ^= ((byte >> 5) & 7u) << 4;
                    bf16x8 ah = *(const bf16x8*)(lds + byte);
                    bf16x8 al = *(const bf16x8*)(lds + 10368 + byte);
                    c4[0][f] = mfma32(ah, bh0, c4[0][f]);
                    c4[0][f] = mfma32(al, bh0, c4[0][f]);
                    c4[0][f] = mfma32(ah, bl0, c4[0][f]);
                    c4[1][f] = mfma32(ah, bh1, c4[1][f]);
                    c4[1][f] = mfma32(al, bh1, c4[1][f]);
                    c4[1][f] = mfma32(ah, bl1, c4[1][f]);
                }
            }
        }

        // ---- per group: om dump -> sample -> dcn gemm
        #pragma unroll
        for (int gg = 0; gg < 2; ++gg) {
            int g = g0 + gg;
            __syncthreads();   // all conv4 MFMAs done (gg=0) / prev gemm sv reads done (gg=1)
            if (col < 27) {
                float pb = pb4[g * 32 + col];
                #pragma unroll
                for (int f = 0; f < 2; ++f)
                    #pragma unroll
                    for (int r = 0; r < 16; ++r) {
                        int pxl = 64 * w + 32 * f + (r & 3) + 8 * (r >> 2) + 4 * khalf;
                        float v = c4[gg][f][r] + pb;
                        v = (col < 18) ? MRM_ * fast_tanh(v) : 1.f / (1.f + __expf(-v));
                        OMB[pxl * 27 + col] = v;
                    }
            }
            __syncthreads();
            // ---- sampler: 1 px per thread, f32
            {
                int px = tid;
                float fx = FLT[px], fy = FLT[256 + px];
                float Yf = (float)(by * 16 + (px >> 4));
                float Xf = (float)(bx * 16 + (px & 15));
                uint b128 = (uint)px * 128, x7 = (uint)(px & 7);
                const float* gb = xg0 + (size_t)(g * 4) * HW;
                #pragma unroll
                for (int k = 0; k < 9; ++k) {
                    float oy = OMB[px * 27 + 2 * k] + fy;
                    float ox = OMB[px * 27 + 2 * k + 1] + fx;
                    float mk = OMB[px * 27 + 18 + k];
                    Bil b = bil(Yf - 1.f + (float)(k / 3) + oy,
                                Xf - 1.f + (float)(k % 3) + ox);
                    uint2 pk; pk.x = 0; pk.y = 0;
                    #pragma unroll
                    for (int cc = 0; cc < 4; ++cc) {
                        const float* p = gb + (size_t)cc * HW;
                        float s = (b.m00 * p[b.i00] + b.m01 * p[b.i01]
                                 + b.m10 * p[b.i10] + b.m11 * p[b.i11]) * mk;
                        ushort hv = bfrn(s);
                        if (cc == 0) pk.x |= hv;
                        else if (cc == 1) pk.x |= (uint)hv << 16;
                        else if (cc == 2) pk.y |= hv;
                        else pk.y |= (uint)hv << 16;
                    }
                    uint byte = b128 + ((((uint)(k >> 1)) ^ x7) << 4) + ((uint)(k & 1) << 3);
                    *(uint2*)(lds + byte) = pk;
                }
            }
            __syncthreads();
            // ---- DCN GEMM: A = sv (bf16), B = dwt frags from global
            #pragma unroll
            for (int kst = 0; kst < 3; ++kst) {
                size_t dbb = (size_t)((g * 3 + kst) * 2) * 512 + (size_t)lane * 8;
                bf16x8 b0 = *(const bf16x8*)(dwtb + dbb);
                bf16x8 b1 = *(const bf16x8*)(dwtb + dbb + 512);
                #pragma unroll
                for (int f = 0; f < 2; ++f) {
                    int pxl = 64 * w + 32 * f + col;
                    uint u = (uint)(kst * 2 + khalf);
                    uint byte = (uint)pxl * 128 + ((u ^ (uint)(pxl & 7)) << 4);
                    bf16x8 a = *(const bf16x8*)(lds + byte);
                    cd[f][0] = mfma32(a, b0, cd[f][0]);
                    cd[f][1] = mfma32(a, b1, cd[f][1]);
                }
            }
        }
    }

    // ---- epilogue: bias + store to output frame slot
    float* base = (n < 5) ? outb + (size_t)n * 64 * HW
                          : outb + (size_t)(n + 2) * 64 * HW;
    #pragma unroll
    for (int f = 0; f < 2; ++f)
        #pragma unroll
        for (int nf = 0; nf < 2; ++nf) {
            int oc = nf * 32 + col;
            float bias = db[oc];
            #pragma unroll
            for (int r = 0; r < 16; ++r) {
                int pxl = 64 * w + 32 * f + (r & 3) + 8 * (r >> 2) + 4 * khalf;
                int y = by * 16 + (pxl >> 4), xx = bx * 16 + (pxl & 15);
                base[(size_t)oc * HW + y * W_ + xx] = cd[f][nf][r] + bias;
            }
        }
}

extern "C" void kernel_launch(void* const* d_in, const int* in_sizes, int n_in,
                              void* d_out, int out_size, void* d_ws, size_t ws_size,
                              hipStream_t stream) {
    (void)in_sizes; (void)n_in; (void)out_size; (void)ws_size;
    const float* x   = (const float*)d_in[0];
    const float* fb  = (const float*)d_in[1];
    const float* ff  = (const float*)d_in[2];
    const float* cw1 = (const float*)d_in[3];
    const float* cb1 = (const float*)d_in[4];
    const float* cw2 = (const float*)d_in[5];
    const float* cb2 = (const float*)d_in[6];
    const float* cw3 = (const float*)d_in[7];
    const float* cb3 = (const float*)d_in[8];
    const float* cw4 = (const float*)d_in[9];
    const float* cb4 = (const float*)d_in[10];
    const float* dw  = (const float*)d_in[11];
    const float* db  = (const float*)d_in[12];
    float* out = (float*)d_out;
    float* ws  = (float*)d_ws;

    // ws layout: bufB (10485760 f32) | cw1t | cw2t | cw3t | w4hi | w4lo | dwtb | pb4
    float* bufA = out;
    float* bufB = ws;
    float* cw1t = ws + 10485760;
    float* cw2t = cw1t + S1;
    float* cw3t = cw2t + S2;
    ushort* w4hi = (ushort*)(cw3t + S2);       // 294912 ushorts
    ushort* w4lo = w4hi + 294912;
    ushort* dwtb = w4lo + 294912;              // 49152 ushorts
    float*  pb4  = (float*)(dwtb + 49152);     // 512 f32

    k_prep1<<<(S1 + 2 * S2 + 255) / 256, 256, 0, stream>>>(cw1, cw2, cw3, cw1t, cw2t, cw3t);
    k_prep4<<<1346, 256, 0, stream>>>(cw4, cb4, dw, w4hi, w4lo, dwtb, pb4);
    k_warp<<<(NP * HW) / 256, 256, 0, stream>>>(x, fb, ff, bufA);
    k_conv<130, 0><<<640, 256, 0, stream>>>(bufA, x, fb, ff, cw1t, cb1, bufB);
    k_conv<64, 1><<<640, 256, 0, stream>>>(bufB, x, fb, ff, cw2t, cb2, bufA);
    k_conv<64, 1><<<640, 256, 0, stream>>>(bufA, x, fb, ff, cw3t, cb3, bufB);

    // zero output frame slots 5 (backward last) and 6 (forward first)
    hipMemsetAsync((char*)d_out + (size_t)5 * C_ * HW * sizeof(float), 0, (size_t)C_ * HW * sizeof(float), stream);
    hipMemsetAsync((char*)d_out + (size_t)6 * C_ * HW * sizeof(float), 0, (size_t)C_ * HW * sizeof(float), stream);

    k_dcn2<<<640, 256, 0, stream>>>(bufB, x, fb, ff, w4hi, w4lo, dwtb, pb4, db, out);
}